// Round 1
// baseline (118.564 us; speedup 1.0000x reference)
//
#include <hip/hip_runtime.h>

#define S 128
#define LOG2F_ 0.6931471805599453f

// stable softplus: log(1+exp(x)) = max(x,0) + log1p(exp(-|x|))
__device__ __forceinline__ float softplus_f(float x) {
    float e = __expf(-fabsf(x));
    return fmaxf(x, 0.0f) + __logf(1.0f + e);
}

// One block per (i, batch) pair. 1024 threads: thread t -> row j = t>>3,
// k-group g = t&7; each thread owns 16 k-elements: k = 32*r4 + 4*g + u.
__global__ __launch_bounds__(1024) void lbp_kernel(
    const float* __restrict__ s_edge,
    const float* __restrict__ s_sib,
    const unsigned char* __restrict__ mask_raw,
    float* __restrict__ out)
{
    const int i  = blockIdx.x & (S - 1);
    const int bb = blockIdx.x >> 7;
    const int t  = threadIdx.x;
    const int j  = t >> 3;
    const int g  = t & 7;

    __shared__ __align__(16) float s_mc[S];    // mask column as 0/1 float
    __shared__ __align__(16) float s_pe0[S];
    __shared__ __align__(16) float s_pe1[S];
    __shared__ __align__(16) float s_db[S];    // db1, later db2
    __shared__ int s_flag;

    // ---- detect mask buffer dtype from first 4096 bytes ----
    // bool8: bytes in {0,1} everywhere -> nonzero at %4!=0 positions.
    // int32 (0/1): only %4==0 bytes nonzero.
    // float32 (0.0/1.0): %4==3 byte is 0x3F for true.
    if (t == 0) s_flag = 0;
    __syncthreads();
    {
        uchar4 v = ((const uchar4*)mask_raw)[t];   // bytes 4t..4t+3 (4KB total)
        int f = 0;
        if ((v.y | v.z | v.w) != 0) f |= 1;
        if (v.w == 0x3F) f |= 2;
        if (f) atomicOr(&s_flag, f);
    }
    __syncthreads();
    const int mode = (s_flag & 2) ? 2 : ((s_flag & 1) ? 0 : 1); // 2=f32,0=bool8,1=int32

    // ---- phase 0: mask column, p_edge column, db1 ----
    if (t < S) {
        const int jj = t;
        const int midx = (bb * S + jj) * S + i;
        int mval;
        if (mode == 0)      mval = mask_raw[midx];
        else if (mode == 1) mval = ((const int*)mask_raw)[midx];
        else                mval = (((const float*)mask_raw)[midx] != 0.0f);
        const float mc = mval ? 1.0f : 0.0f;
        s_mc[jj] = mc;
        const int eidx = ((bb * S + jj) * S + i) * 2;
        const float pe0 = s_edge[eidx];
        const float pe1 = s_edge[eidx + 1];
        s_pe0[jj] = pe0;
        s_pe1[jj] = pe1;
        s_db[jj]  = mc * (pe1 - pe0);   // db1[k]: b1 = pe * fmask
    }
    __syncthreads();

    // ---- phase 1: c = softplus(sv) - log2 ; d1 = db1[k] + c ----
    float c_[16], d_[16];
    const int sbase = ((bb * S + j) * S + i) * S;   // max ~16.7M, fits int
    #pragma unroll
    for (int r4 = 0; r4 < 4; ++r4) {
        const int k0 = 32 * r4 + 4 * g;
        const float4 sv = *(const float4*)(s_sib + sbase + k0);
        const float4 db = *(const float4*)(s_db + k0);
        float cc;
        cc = softplus_f(sv.x) - LOG2F_; c_[4*r4+0] = cc; d_[4*r4+0] = db.x + cc;
        cc = softplus_f(sv.y) - LOG2F_; c_[4*r4+1] = cc; d_[4*r4+1] = db.y + cc;
        cc = softplus_f(sv.z) - LOG2F_; c_[4*r4+2] = cc; d_[4*r4+2] = db.z + cc;
        cc = softplus_f(sv.w) - LOG2F_; c_[4*r4+3] = cc; d_[4*r4+3] = db.w + cc;
    }

    // ---- phase 2: b2 row-sums from m1(d1); write db2 ----
    float p0 = 0.0f, p1 = 0.0f;
    #pragma unroll
    for (int r4 = 0; r4 < 4; ++r4) {
        const int k0 = 32 * r4 + 4 * g;
        const float4 mc4 = *(const float4*)(s_mc + k0);
        #pragma unroll
        for (int u = 0; u < 4; ++u) {
            const float mcv = (&mc4.x)[u];
            const float dd  = d_[4*r4+u];
            const float sp  = softplus_f(dd);
            p0 -= mcv * sp;              // m0 = -softplus(d)
            p1 += mcv * (dd - sp);       // m1 = d - softplus(d)
        }
    }
    p0 += __shfl_xor(p0, 1); p1 += __shfl_xor(p1, 1);
    p0 += __shfl_xor(p0, 2); p1 += __shfl_xor(p1, 2);
    p0 += __shfl_xor(p0, 4); p1 += __shfl_xor(p1, 4);
    const float mcj = s_mc[j];

    __syncthreads();                    // everyone done reading db1
    if (g == 0) {
        const float b20 = mcj * (s_pe0[j] + p0);
        const float b21 = mcj * (s_pe1[j] + p1);
        s_db[j] = b21 - b20;            // db2
    }
    __syncthreads();

    // ---- phase 3: d2 = db2[k] - d1 + c ; b3 row-sums ; output ----
    float q0 = 0.0f, q1 = 0.0f;
    #pragma unroll
    for (int r4 = 0; r4 < 4; ++r4) {
        const int k0 = 32 * r4 + 4 * g;
        const float4 db2 = *(const float4*)(s_db + k0);
        const float4 mc4 = *(const float4*)(s_mc + k0);
        #pragma unroll
        for (int u = 0; u < 4; ++u) {
            const float mcv = (&mc4.x)[u];
            const float dd  = (&db2.x)[u] - d_[4*r4+u] + c_[4*r4+u];
            const float sp  = softplus_f(dd);
            q0 -= mcv * sp;
            q1 += mcv * (dd - sp);
        }
    }
    q0 += __shfl_xor(q0, 1); q1 += __shfl_xor(q1, 1);
    q0 += __shfl_xor(q0, 2); q1 += __shfl_xor(q1, 2);
    q0 += __shfl_xor(q0, 4); q1 += __shfl_xor(q1, 4);

    if (g == 0) {
        const float o0 = mcj * (s_pe0[j] + q0);
        const float o1 = mcj * (s_pe1[j] + q1);
        const int oidx = ((bb * S + j) * S + i) * 2;
        *(float2*)(out + oidx) = make_float2(o0, o1);
    }
}

extern "C" void kernel_launch(void* const* d_in, const int* in_sizes, int n_in,
                              void* d_out, int out_size, void* d_ws, size_t ws_size,
                              hipStream_t stream) {
    const float* s_edge = (const float*)d_in[0];
    const float* s_sib  = (const float*)d_in[1];
    const unsigned char* mask = (const unsigned char*)d_in[2];
    float* out = (float*)d_out;

    const int B = in_sizes[0] / (S * S * 2);   // 8
    lbp_kernel<<<dim3(B * S), dim3(1024), 0, stream>>>(s_edge, s_sib, mask, out);
}

// Round 2
// 99.349 us; speedup vs baseline: 1.1934x; 1.1934x over previous
//
#include <hip/hip_runtime.h>

#define S 128
#define LOG2E 1.4426950408889634f
#define LN2F  0.6931471805599453f

static __device__ __forceinline__ float fexp2(float x) {
#if __has_builtin(__builtin_amdgcn_exp2f)
    return __builtin_amdgcn_exp2f(x);
#else
    return exp2f(x);
#endif
}
static __device__ __forceinline__ float flog2(float x) {
#if __has_builtin(__builtin_amdgcn_logf)
    return __builtin_amdgcn_logf(x);
#else
    return log2f(x);
#endif
}
// base-2 softplus: log2(1 + 2^x) = max(x,0) + log2(1 + 2^(-|x|))
static __device__ __forceinline__ float sp2(float x) {
    float a = fminf(x, -x);                 // -|x| (one v_min with neg modifier)
    float l = flog2(1.0f + fexp2(a));
    return fmaxf(x, 0.0f) + l;
}

// One block per (i, batch). 1024 threads: t -> row j = t>>3, k-group g = t&7,
// each thread streams 16 k-elements (4x float4).
//
// Math (hat = scaled by log2(e); out multiplies back by ln2):
//   db1[k] = mc[k]*(pe1[k]-pe0[k])
//   Kd = sum_k db1[k];  N = sum_k mc[k]
//   Crow[j] = sum_k mc[k]*sp2(sv[j,k])
//   db2[j] = mc[j]*(dpe[j] + Kd + Crow[j] - N)       (since c = sp2 - 1)
//   d2[k]  = db2[k] - db1[k]                          (j-independent!)
//   T0 = sum_k mc[k]*sp2(d2[k]);  T1 = sum_k mc[k]*d2[k]
//   out[j,0] = ln2*mc[j]*(pe0[j] - T0)
//   out[j,1] = ln2*mc[j]*(pe1[j] + T1 - T0)
__global__ __launch_bounds__(1024) void lbp_kernel(
    const float* __restrict__ s_edge,
    const float* __restrict__ s_sib,
    const unsigned char* __restrict__ mask_raw,
    float* __restrict__ out)
{
    const int i  = blockIdx.x & (S - 1);
    const int bb = blockIdx.x >> 7;
    const int t  = threadIdx.x;
    const int j  = t >> 3;
    const int g  = t & 7;

    __shared__ __align__(16) float s_mc[S];
    __shared__ __align__(16) float s_pe0[S];   // pe0 * log2e
    __shared__ __align__(16) float s_pe1[S];   // pe1 * log2e
    __shared__ __align__(16) float s_db1[S];
    __shared__ __align__(16) float s_db2[S];
    __shared__ __align__(16) float s_v0[S];
    __shared__ __align__(16) float s_v1[S];
    __shared__ float s_Kd, s_N, s_T0, s_T1;
    __shared__ int s_flag;

    // ---- detect mask buffer dtype from first 4096 bytes ----
    if (t == 0) s_flag = 0;
    __syncthreads();
    {
        uchar4 v = ((const uchar4*)mask_raw)[t];
        int f = 0;
        if ((v.y | v.z | v.w) != 0) f |= 1;
        if (v.w == 0x3F) f |= 2;
        if (f) atomicOr(&s_flag, f);
    }
    __syncthreads();
    const int mode = (s_flag & 2) ? 2 : ((s_flag & 1) ? 0 : 1); // 2=f32,0=bool8,1=int32

    // ---- phase 0: mask column, scaled p_edge column, db1 ----
    if (t < S) {
        const int midx = (bb * S + t) * S + i;
        int mval;
        if (mode == 0)      mval = mask_raw[midx];
        else if (mode == 1) mval = ((const int*)mask_raw)[midx];
        else                mval = (((const float*)mask_raw)[midx] != 0.0f);
        const float mc = mval ? 1.0f : 0.0f;
        const int eidx = ((bb * S + t) * S + i) * 2;
        const float pe0 = s_edge[eidx]     * LOG2E;
        const float pe1 = s_edge[eidx + 1] * LOG2E;
        s_mc[t]  = mc;
        s_pe0[t] = pe0;
        s_pe1[t] = pe1;
        s_db1[t] = mc * (pe1 - pe0);
    }
    __syncthreads();

    // ---- wave 0: scalars Kd = sum(db1), N = sum(mc) ----
    if (t < 64) {
        float kd = s_db1[t] + s_db1[t + 64];
        float nn = s_mc[t]  + s_mc[t + 64];
        #pragma unroll
        for (int o = 1; o < 64; o <<= 1) {
            kd += __shfl_xor(kd, o);
            nn += __shfl_xor(nn, o);
        }
        if (t == 0) { s_Kd = kd; s_N = nn; }
    }

    // ---- phase B: Crow[j] = sum_k mc[k]*sp2(sv_hat) ---- (only O(S^2) work)
    float acc = 0.0f;
    const int sbase = ((bb * S + j) * S + i) * S;
    #pragma unroll
    for (int r4 = 0; r4 < 4; ++r4) {
        const int k0 = 32 * r4 + 4 * g;
        const float4 sv  = *(const float4*)(s_sib + sbase + k0);
        const float4 mc4 = *(const float4*)(s_mc + k0);
        acc = fmaf(mc4.x, sp2(LOG2E * sv.x), acc);
        acc = fmaf(mc4.y, sp2(LOG2E * sv.y), acc);
        acc = fmaf(mc4.z, sp2(LOG2E * sv.z), acc);
        acc = fmaf(mc4.w, sp2(LOG2E * sv.w), acc);
    }
    acc += __shfl_xor(acc, 1);
    acc += __shfl_xor(acc, 2);
    acc += __shfl_xor(acc, 4);
    __syncthreads();           // s_Kd/s_N visible; everyone done with phase-B reads

    if (g == 0) {
        const float mcj = s_mc[j];
        s_db2[j] = mcj * ((s_pe1[j] - s_pe0[j]) + s_Kd + acc - s_N);
    }
    __syncthreads();

    // ---- phase C (O(S)): d2 = db2 - db1; masked sums of sp2(d2) and d2 ----
    if (t < S) {
        const float mc = s_mc[t];
        const float d2 = s_db2[t] - s_db1[t];
        s_v0[t] = mc * sp2(d2);
        s_v1[t] = mc * d2;
    }
    __syncthreads();
    if (t < 64) {
        float a0 = s_v0[t] + s_v0[t + 64];
        float a1 = s_v1[t] + s_v1[t + 64];
        #pragma unroll
        for (int o = 1; o < 64; o <<= 1) {
            a0 += __shfl_xor(a0, o);
            a1 += __shfl_xor(a1, o);
        }
        if (t == 0) { s_T0 = a0; s_T1 = a1; }
    }
    __syncthreads();

    // ---- output ----
    if (t < S) {
        const float mc = s_mc[t];
        const float o0 = LN2F * mc * (s_pe0[t] - s_T0);
        const float o1 = LN2F * mc * (s_pe1[t] + s_T1 - s_T0);
        const int oidx = ((bb * S + t) * S + i) * 2;
        *(float2*)(out + oidx) = make_float2(o0, o1);
    }
}

extern "C" void kernel_launch(void* const* d_in, const int* in_sizes, int n_in,
                              void* d_out, int out_size, void* d_ws, size_t ws_size,
                              hipStream_t stream) {
    const float* s_edge = (const float*)d_in[0];
    const float* s_sib  = (const float*)d_in[1];
    const unsigned char* mask = (const unsigned char*)d_in[2];
    float* out = (float*)d_out;

    const int B = in_sizes[0] / (S * S * 2);   // 8
    lbp_kernel<<<dim3(B * S), dim3(1024), 0, stream>>>(s_edge, s_sib, mask, out);
}